// Round 10
// baseline (35.214 us; speedup 1.0000x reference)
//
#include <hip/hip_runtime.h>
#include <hip/hip_fp16.h>

#define NUM_F  39
#define NUM_P  741      // 39*38/2
#define NPAD   768      // 48 tiles * 16
#define DIM    64
#define WSTRH  72       // Wt fp16 row stride in halves (144 B, 16B-aligned)
#define ESTRB  80       // E fp8 row stride in BYTES (16B-aligned, odd*16 -> bank spread)
#define SCALE  1024.0f  // E pre-scale; products carry 2^20
#define INVSC2 (1.0f/1048576.0f)

typedef float    f32x4 __attribute__((ext_vector_type(4)));
typedef float    f32x2 __attribute__((ext_vector_type(2)));
typedef _Float16 f16x8 __attribute__((ext_vector_type(8)));
typedef __fp16   h16x2 __attribute__((ext_vector_type(2)));   // cvt_pkrtz result type

union B8 { f16x8 v; h16x2 g[4]; };

__global__ __launch_bounds__(256, 3) void afm_fp8e(
    const int*   __restrict__ feat_index,   // [B, F]
    const float* __restrict__ feat_value,   // [B, F]
    const float* __restrict__ fo_w,         // [NUM_FEATS, 1]
    const float* __restrict__ emb_table,    // [NUM_FEATS, 64]
    const float* __restrict__ att_W,        // [64, 64] (d, a)
    const float* __restrict__ att_b,        // [64]
    const float* __restrict__ att_h,        // [64]
    const float* __restrict__ p_vec,        // [64]
    const float* __restrict__ bias,         // [1]
    float*       __restrict__ out)          // [B]
{
    const int b    = blockIdx.x;
    const int t    = threadIdx.x;
    const int wave = t >> 6;
    const int lane = t & 63;
    const int la   = lane & 15;   // pair-within-tile (B col / C col)
    const int lg   = lane >> 4;   // k-group / C row-group

    // E rows in fp8, k-interleaved: row bytes [g*16, g*16+8) hold k=g*8+j (frag0);
    // bytes [g*16+8, g*16+16) hold k=32+g*8+j (frag1) -> lane reads ONE b128 at lg*16
    __shared__ int4    e8[NUM_F * (ESTRB / 16)];       // 39 * 80B
    __shared__ __half  Wt[DIM][WSTRH];                 // W^T fp16: Wt[a][d]
    __shared__ float2  sq_s[NPAD];                     // {sig, q'}
    __shared__ float   b_lds[DIM], h_lds[DIM], pv_lds[DIM];
    __shared__ int     s_idx[NUM_F];
    __shared__ float   s_fv[NUM_F];
    __shared__ float   s_yfirst;
    __shared__ float   wred[12];

    // ---------------- phase 0: staging ----------------
    int   my_idx = 0;
    float my_fv  = 0.f;
    if (t < NUM_F) {
        my_idx   = feat_index[b * NUM_F + t];
        my_fv    = feat_value[b * NUM_F + t];
        s_idx[t] = my_idx;
        s_fv[t]  = my_fv;
    }
    if (t < DIM) {
        b_lds[t]  = att_b[t] * (SCALE * SCALE);   // fold 2^20 into C-init
        h_lds[t]  = att_h[t] * INVSC2;            // fold 2^-20 into h
        pv_lds[t] = p_vec[t];
    }

    // W^T -> fp16 LDS, coalesced reads AND b32 writes
    for (int q2 = t; q2 < DIM * DIM / 2; q2 += 256) {
        int a  = q2 & 63;
        int dp = q2 >> 6;             // d-pair index
        float w0 = att_W[dp * 128 + a];
        float w1 = att_W[dp * 128 + 64 + a];
        *(h16x2*)&Wt[a][dp * 2] = __builtin_amdgcn_cvt_pkrtz(w0, w1);
    }

    // y_first: wave 0 butterfly
    float yf = (t < NUM_F) ? fo_w[my_idx] * my_fv : 0.f;
    if (wave == 0) {
        #pragma unroll
        for (int m = 1; m < 64; m <<= 1) yf += __shfl_xor(yf, m);
        if (t == 0) s_yfirst = yf;
    }
    __syncthreads();

    // ---------------- phase 1: E staging (fp8, k-interleaved) ----------------
    // NUM_F*8 = 312 work items > 256 threads -> MUST grid-stride (R9 bug: if() missed rows 32..38)
    for (int q = t; q < NUM_F * 8; q += 256) {
        const int f = q >> 3, g = q & 7;
        const float4* emb4 = (const float4*)emb_table;
        float4 v0 = emb4[(size_t)s_idx[f] * 16 + g * 2];
        float4 v1 = emb4[(size_t)s_idx[f] * 16 + g * 2 + 1];
        float s = s_fv[f] * SCALE;
        int d0 = __builtin_amdgcn_cvt_pk_fp8_f32(v0.x * s, v0.y * s, 0, 0);
        d0     = __builtin_amdgcn_cvt_pk_fp8_f32(v0.z * s, v0.w * s, d0, 1);
        int d1 = __builtin_amdgcn_cvt_pk_fp8_f32(v1.x * s, v1.y * s, 0, 0);
        d1     = __builtin_amdgcn_cvt_pk_fp8_f32(v1.z * s, v1.w * s, d1, 1);
        const int off = f * ESTRB + (g & 3) * 16 + (g >> 2) * 8;
        *(int2*)((char*)e8 + off) = make_int2(d0, d1);
    }
    __syncthreads();

    // ---------------- stationary fragments ----------------
    const f16x8 WA00 = *(const f16x8*)&Wt[ 0 + la][ 0 + lg * 8];
    const f16x8 WA01 = *(const f16x8*)&Wt[ 0 + la][32 + lg * 8];
    const f16x8 WA10 = *(const f16x8*)&Wt[16 + la][ 0 + lg * 8];
    const f16x8 WA11 = *(const f16x8*)&Wt[16 + la][32 + lg * 8];
    const f16x8 WA20 = *(const f16x8*)&Wt[32 + la][ 0 + lg * 8];
    const f16x8 WA21 = *(const f16x8*)&Wt[32 + la][32 + lg * 8];
    const f16x8 WA30 = *(const f16x8*)&Wt[48 + la][ 0 + lg * 8];
    const f16x8 WA31 = *(const f16x8*)&Wt[48 + la][32 + lg * 8];

    f16x8 PA0 = (f16x8)(_Float16)0.f;
    f16x8 PA1 = (f16x8)(_Float16)0.f;
    if (la == 0) {
        #pragma unroll
        for (int j = 0; j < 8; ++j) {
            PA0[j] = (_Float16)pv_lds[     lg * 8 + j];
            PA1[j] = (_Float16)pv_lds[32 + lg * 8 + j];
        }
    }

    const f32x4 b40 = *(const f32x4*)&b_lds[ 0 + lg * 4];
    const f32x4 b41 = *(const f32x4*)&b_lds[16 + lg * 4];
    const f32x4 b42 = *(const f32x4*)&b_lds[32 + lg * 4];
    const f32x4 b43 = *(const f32x4*)&b_lds[48 + lg * 4];
    const f32x4 h40 = *(const f32x4*)&h_lds[ 0 + lg * 4];
    const f32x4 h41 = *(const f32x4*)&h_lds[16 + lg * 4];
    const f32x4 h42 = *(const f32x4*)&h_lds[32 + lg * 4];
    const f32x4 h43 = *(const f32x4*)&h_lds[48 + lg * 4];
    const f32x4 z4  = {0.f, 0.f, 0.f, 0.f};

    const char* e_base = (const char*)e8;
    const int   lgo    = lg * 16;

    // ---------------- phase 2: pair-tile loop ----------------
    #pragma unroll 1
    for (int it = 0; it < 12; ++it) {
        const int tile = wave + it * 4;        // < 48
        const int p    = (tile << 4) + la;
        const int pc   = (p < NUM_P - 1) ? p : (NUM_P - 1);

        // closed-form triangular index: r,c from pc (exact; margin >= 0.026)
        const float disc = (float)(5929 - 8 * pc);
        const int r  = (int)((77.0f - sqrtf(disc)) * 0.5f);
        const int c  = pc - ((r * (77 - r)) >> 1) + r + 1;
        const int ro = r * ESTRB;
        const int co = c * ESTRB;

        // ONE b128 per row: fp8 x16 = frag0 (8B) | frag1 (8B)
        const int4 er = *(const int4*)(e_base + ro + lgo);
        const int4 ec = *(const int4*)(e_base + co + lgo);

        // upconvert + multiply + pack to f16 B-frags (products carry 2^20)
        B8 B0, B1;
        {
            f32x2 ra = __builtin_amdgcn_cvt_pk_f32_fp8(er.x, 0);
            f32x2 rb = __builtin_amdgcn_cvt_pk_f32_fp8(er.x, 1);
            f32x2 rc = __builtin_amdgcn_cvt_pk_f32_fp8(er.y, 0);
            f32x2 rd = __builtin_amdgcn_cvt_pk_f32_fp8(er.y, 1);
            f32x2 ca = __builtin_amdgcn_cvt_pk_f32_fp8(ec.x, 0);
            f32x2 cb = __builtin_amdgcn_cvt_pk_f32_fp8(ec.x, 1);
            f32x2 cc = __builtin_amdgcn_cvt_pk_f32_fp8(ec.y, 0);
            f32x2 cd = __builtin_amdgcn_cvt_pk_f32_fp8(ec.y, 1);
            B0.g[0] = __builtin_amdgcn_cvt_pkrtz(ra.x * ca.x, ra.y * ca.y);
            B0.g[1] = __builtin_amdgcn_cvt_pkrtz(rb.x * cb.x, rb.y * cb.y);
            B0.g[2] = __builtin_amdgcn_cvt_pkrtz(rc.x * cc.x, rc.y * cc.y);
            B0.g[3] = __builtin_amdgcn_cvt_pkrtz(rd.x * cd.x, rd.y * cd.y);
        }
        {
            f32x2 ra = __builtin_amdgcn_cvt_pk_f32_fp8(er.z, 0);
            f32x2 rb = __builtin_amdgcn_cvt_pk_f32_fp8(er.z, 1);
            f32x2 rc = __builtin_amdgcn_cvt_pk_f32_fp8(er.w, 0);
            f32x2 rd = __builtin_amdgcn_cvt_pk_f32_fp8(er.w, 1);
            f32x2 ca = __builtin_amdgcn_cvt_pk_f32_fp8(ec.z, 0);
            f32x2 cb = __builtin_amdgcn_cvt_pk_f32_fp8(ec.z, 1);
            f32x2 cc = __builtin_amdgcn_cvt_pk_f32_fp8(ec.w, 0);
            f32x2 cd = __builtin_amdgcn_cvt_pk_f32_fp8(ec.w, 1);
            B1.g[0] = __builtin_amdgcn_cvt_pkrtz(ra.x * ca.x, ra.y * ca.y);
            B1.g[1] = __builtin_amdgcn_cvt_pkrtz(rb.x * cb.x, rb.y * cb.y);
            B1.g[2] = __builtin_amdgcn_cvt_pkrtz(rc.x * cc.x, rc.y * cc.y);
            B1.g[3] = __builtin_amdgcn_cvt_pkrtz(rd.x * cd.x, rd.y * cd.y);
        }

        // Z'^T tiles: D[a][pair]; C-init = b * 2^20
        f32x4 a0 = __builtin_amdgcn_mfma_f32_16x16x32_f16(WA00, B0.v, b40, 0, 0, 0);
        f32x4 a1 = __builtin_amdgcn_mfma_f32_16x16x32_f16(WA10, B0.v, b41, 0, 0, 0);
        f32x4 a2 = __builtin_amdgcn_mfma_f32_16x16x32_f16(WA20, B0.v, b42, 0, 0, 0);
        f32x4 a3 = __builtin_amdgcn_mfma_f32_16x16x32_f16(WA30, B0.v, b43, 0, 0, 0);
        f32x4 aq = __builtin_amdgcn_mfma_f32_16x16x32_f16(PA0,  B0.v, z4,  0, 0, 0);
        a0 = __builtin_amdgcn_mfma_f32_16x16x32_f16(WA01, B1.v, a0, 0, 0, 0);
        a1 = __builtin_amdgcn_mfma_f32_16x16x32_f16(WA11, B1.v, a1, 0, 0, 0);
        a2 = __builtin_amdgcn_mfma_f32_16x16x32_f16(WA21, B1.v, a2, 0, 0, 0);
        a3 = __builtin_amdgcn_mfma_f32_16x16x32_f16(WA31, B1.v, a3, 0, 0, 0);
        aq = __builtin_amdgcn_mfma_f32_16x16x32_f16(PA1,  B1.v, aq, 0, 0, 0);

        // epilogue: sig = sum_a relu(z')*h'  (h' carries 2^-20)
        float s0 = fmaxf(a0[0], 0.f) * h40[0];
        float s1 = fmaxf(a1[0], 0.f) * h41[0];
        float s2 = fmaxf(a2[0], 0.f) * h42[0];
        float s3 = fmaxf(a3[0], 0.f) * h43[0];
        s0 = fmaf(fmaxf(a0[1], 0.f), h40[1], s0);
        s1 = fmaf(fmaxf(a1[1], 0.f), h41[1], s1);
        s2 = fmaf(fmaxf(a2[1], 0.f), h42[1], s2);
        s3 = fmaf(fmaxf(a3[1], 0.f), h43[1], s3);
        s0 = fmaf(fmaxf(a0[2], 0.f), h40[2], s0);
        s1 = fmaf(fmaxf(a1[2], 0.f), h41[2], s1);
        s2 = fmaf(fmaxf(a2[2], 0.f), h42[2], s2);
        s3 = fmaf(fmaxf(a3[2], 0.f), h43[2], s3);
        s0 = fmaf(fmaxf(a0[3], 0.f), h40[3], s0);
        s1 = fmaf(fmaxf(a1[3], 0.f), h41[3], s1);
        s2 = fmaf(fmaxf(a2[3], 0.f), h42[3], s2);
        s3 = fmaf(fmaxf(a3[3], 0.f), h43[3], s3);
        float ts = (s0 + s1) + (s2 + s3);
        ts += __shfl_xor(ts, 16);
        ts += __shfl_xor(ts, 32);

        if (lg == 0 && p < NUM_P) {
            sq_s[p] = make_float2(ts, aq[0]);   // q' (2^20-scaled) at C row 0
        }
    }
    __syncthreads();

    // ---------------- phase 3: softmax + pooling ----------------
    float sv0, sv1, sv2, qv0, qv1, qv2;
    {
        float2 x0 = sq_s[t];
        float2 x1 = sq_s[t + 256];
        bool ok2 = (t + 512) < NUM_P;
        float2 x2 = ok2 ? sq_s[t + 512] : make_float2(-1e30f, 0.f);
        sv0 = x0.x; qv0 = x0.y;
        sv1 = x1.x; qv1 = x1.y;
        sv2 = x2.x; qv2 = x2.y;
        if (t + 256 >= NUM_P) { sv1 = -1e30f; qv1 = 0.f; }
        if (t >= NUM_P)       { sv0 = -1e30f; qv0 = 0.f; }
    }

    float m3 = fmaxf(fmaxf(sv0, sv1), sv2);
    #pragma unroll
    for (int mm = 1; mm < 64; mm <<= 1) m3 = fmaxf(m3, __shfl_xor(m3, mm));
    if (lane == 0) wred[wave] = m3;
    __syncthreads();
    const float M = fmaxf(fmaxf(wred[0], wred[1]), fmaxf(wred[2], wred[3]));

    float e0 = __expf(sv0 - M);
    float e1 = __expf(sv1 - M);
    float e2 = __expf(sv2 - M);
    float S  = e0 + e1 + e2;
    float Q  = fmaf(e0, qv0, fmaf(e1, qv1, e2 * qv2));
    #pragma unroll
    for (int mm = 1; mm < 64; mm <<= 1) {
        S += __shfl_xor(S, mm);
        Q += __shfl_xor(Q, mm);
    }
    if (lane == 0) { wred[4 + wave] = S; wred[8 + wave] = Q; }
    __syncthreads();

    if (t == 0) {
        const float Ssum = wred[4] + wred[5] + wred[6] + wred[7];
        const float Qsum = wred[8] + wred[9] + wred[10] + wred[11];
        const float att_pool = (Qsum * INVSC2) / Ssum;   // undo 2^20 on q
        const float x = bias[0] + s_yfirst + att_pool;
        out[b] = 1.f / (1.f + __expf(-x));
    }
}

extern "C" void kernel_launch(void* const* d_in, const int* in_sizes, int n_in,
                              void* d_out, int out_size, void* d_ws, size_t ws_size,
                              hipStream_t stream) {
    const int*   feat_index = (const int*)  d_in[0];
    const float* feat_value = (const float*)d_in[1];
    const float* fo_w       = (const float*)d_in[2];
    const float* emb_table  = (const float*)d_in[3];
    const float* att_W      = (const float*)d_in[4];
    const float* att_b      = (const float*)d_in[5];
    const float* att_h      = (const float*)d_in[6];
    const float* p_vec      = (const float*)d_in[7];
    const float* bias       = (const float*)d_in[8];
    float*       out        = (float*)d_out;

    const int B = in_sizes[0] / NUM_F;   // 2048

    afm_fp8e<<<B, 256, 0, stream>>>(feat_index, feat_value, fo_w, emb_table,
                                    att_W, att_b, att_h, p_vec, bias, out);
}

// Round 11
// 30.176 us; speedup vs baseline: 1.1670x; 1.1670x over previous
//
#include <hip/hip_runtime.h>
#include <hip/hip_fp16.h>

#define NUM_F  39
#define NUM_P  741      // 39*38/2
#define NPAD   768      // 48 tiles * 16
#define DIM    64
#define ESTRH  72       // fp16 row stride in halves; 144 B rows (16B aligned)
#define EROWB  (NUM_F * ESTRH * 2)   // 5616 B per batch-row block

typedef float    f32x4 __attribute__((ext_vector_type(4)));
typedef _Float16 f16x8 __attribute__((ext_vector_type(8)));

__global__ __launch_bounds__(512, 4) void afm_2row(
    const int*   __restrict__ feat_index,   // [B, F]
    const float* __restrict__ feat_value,   // [B, F]
    const float* __restrict__ fo_w,         // [NUM_FEATS, 1]
    const float* __restrict__ emb_table,    // [NUM_FEATS, 64]
    const float* __restrict__ att_W,        // [64, 64] (d, a)
    const float* __restrict__ att_b,        // [64]
    const float* __restrict__ att_h,        // [64]
    const float* __restrict__ p_vec,        // [64]
    const float* __restrict__ bias,         // [1]
    float*       __restrict__ out)          // [B]
{
    const int blk  = blockIdx.x;            // handles batch rows 2*blk, 2*blk+1
    const int t    = threadIdx.x;
    const int wave = t >> 6;
    const int lane = t & 63;
    const int row  = wave >> 2;             // 0 or 1
    const int wv   = wave & 3;              // wave-within-row
    const int la   = lane & 15;             // pair-within-tile (B col / C col)
    const int lg   = lane >> 4;             // k-group / C row-group

    __shared__ __half       e_lds[2][NUM_F][ESTRH];  // scaled embeddings, fp16, per row
    __shared__ __half       Wt[DIM][ESTRH];          // W^T fp16: Wt[a][d] (shared)
    __shared__ float2       sq_s[2][NPAD];           // {sig, q} per row
    __shared__ float        b_lds[DIM], h_lds[DIM], pv_lds[DIM];
    __shared__ unsigned int pairOff[NPAD];           // r*144 | (c*144 << 16)
    __shared__ int          s_idx[2 * NUM_F];
    __shared__ float        s_fv[2 * NUM_F];
    __shared__ float        yf_s[2 * NUM_F];
    __shared__ float        s_yfirst[2];
    __shared__ float        wredM[8], wredS[8], wredQ[8];

    // ---------------- phase 0: staging (write-only, one barrier) ----------------
    if (t < 2 * NUM_F) {
        int   idx = feat_index[blk * 2 * NUM_F + t];
        float fv  = feat_value[blk * 2 * NUM_F + t];
        s_idx[t]  = idx;
        s_fv[t]   = fv;
        yf_s[t]   = fo_w[idx] * fv;
    }
    if (t < DIM) {
        b_lds[t]  = att_b[t];
        h_lds[t]  = att_h[t];
        pv_lds[t] = p_vec[t];
    }
    if (t >= 128 && t < 128 + NUM_F) {   // pair table (one wave, independent of loads above)
        int r = t - 128, off = r * (2 * NUM_F - r - 1) / 2;
        const unsigned int rb = (unsigned int)(r * (ESTRH * 2));
        for (int c = r + 1; c < NUM_F; ++c) {
            pairOff[off] = rb | ((unsigned int)(c * (ESTRH * 2)) << 16);
            ++off;
        }
    }
    if (t >= 192 && t < 192 + (NPAD - NUM_P)) pairOff[NUM_P + (t - 192)] = 0;

    // W^T -> fp16 LDS (coalesced float reads; 4 iters at 512 threads)
    for (int q = t; q < DIM * DIM; q += 512) {
        int d = q >> 6, a = q & 63;
        Wt[a][d] = (__half)(_Float16)att_W[q];
    }
    __syncthreads();

    // ---------------- phase 1: E staging (fp16) + y_first reduction ----------------
    {
        const float4* emb4 = (const float4*)emb_table;
        for (int q = t; q < 2 * NUM_F * 8; q += 512) {     // 624 items
            int f = q >> 3, d8 = q & 7;                    // f in [0,78)
            int rr = (f >= NUM_F);
            int ff = f - rr * NUM_F;
            float4 v0 = emb4[(size_t)s_idx[f] * 16 + d8 * 2];
            float4 v1 = emb4[(size_t)s_idx[f] * 16 + d8 * 2 + 1];
            float fv = s_fv[f];
            f16x8 hv;
            hv[0] = (_Float16)(v0.x * fv);
            hv[1] = (_Float16)(v0.y * fv);
            hv[2] = (_Float16)(v0.z * fv);
            hv[3] = (_Float16)(v0.w * fv);
            hv[4] = (_Float16)(v1.x * fv);
            hv[5] = (_Float16)(v1.y * fv);
            hv[6] = (_Float16)(v1.z * fv);
            hv[7] = (_Float16)(v1.w * fv);
            *(f16x8*)&e_lds[rr][ff][d8 * 8] = hv;
        }
    }
    // y_first per row: wave 0 -> row 0, wave 4 -> row 1
    if (wv == 0) {
        float yf = (lane < NUM_F) ? yf_s[row * NUM_F + lane] : 0.f;
        #pragma unroll
        for (int m = 1; m < 64; m <<= 1) yf += __shfl_xor(yf, m);
        if (lane == 0) s_yfirst[row] = yf;
    }
    __syncthreads();

    // ---------------- stationary fragments (named SSA) ----------------
    const f16x8 WA00 = *(const f16x8*)&Wt[ 0 + la][ 0 + lg * 8];
    const f16x8 WA01 = *(const f16x8*)&Wt[ 0 + la][32 + lg * 8];
    const f16x8 WA10 = *(const f16x8*)&Wt[16 + la][ 0 + lg * 8];
    const f16x8 WA11 = *(const f16x8*)&Wt[16 + la][32 + lg * 8];
    const f16x8 WA20 = *(const f16x8*)&Wt[32 + la][ 0 + lg * 8];
    const f16x8 WA21 = *(const f16x8*)&Wt[32 + la][32 + lg * 8];
    const f16x8 WA30 = *(const f16x8*)&Wt[48 + la][ 0 + lg * 8];
    const f16x8 WA31 = *(const f16x8*)&Wt[48 + la][32 + lg * 8];

    f16x8 PA0 = (f16x8)(_Float16)0.f;
    f16x8 PA1 = (f16x8)(_Float16)0.f;
    if (la == 0) {
        #pragma unroll
        for (int j = 0; j < 8; ++j) {
            PA0[j] = (_Float16)pv_lds[     lg * 8 + j];
            PA1[j] = (_Float16)pv_lds[32 + lg * 8 + j];
        }
    }

    const f32x4 b40 = *(const f32x4*)&b_lds[ 0 + lg * 4];
    const f32x4 b41 = *(const f32x4*)&b_lds[16 + lg * 4];
    const f32x4 b42 = *(const f32x4*)&b_lds[32 + lg * 4];
    const f32x4 b43 = *(const f32x4*)&b_lds[48 + lg * 4];
    const f32x4 h40 = *(const f32x4*)&h_lds[ 0 + lg * 4];
    const f32x4 h41 = *(const f32x4*)&h_lds[16 + lg * 4];
    const f32x4 h42 = *(const f32x4*)&h_lds[32 + lg * 4];
    const f32x4 h43 = *(const f32x4*)&h_lds[48 + lg * 4];
    const f32x4 z4  = {0.f, 0.f, 0.f, 0.f};

    const char* e_base = (const char*)&e_lds[row][0][0];
    const int   lgo    = lg * 16;

    // ---------------- phase 2: pair-tile loop (row's 47 tiles over 4 waves) ----------------
    #pragma unroll 1
    for (int it = 0; it < 12; ++it) {
        const int tile = wv + it * 4;          // < 48
        const int p    = (tile << 4) + la;
        const unsigned rc = pairOff[p];
        const unsigned ro = rc & 0xFFFFu;
        const unsigned co = rc >> 16;

        const f16x8 er0 = *(const f16x8*)(e_base + ro + lgo);
        const f16x8 er1 = *(const f16x8*)(e_base + ro + lgo + 64);
        const f16x8 ec0 = *(const f16x8*)(e_base + co + lgo);
        const f16x8 ec1 = *(const f16x8*)(e_base + co + lgo + 64);
        const f16x8 B0 = er0 * ec0;            // v_pk_mul_f16
        const f16x8 B1 = er1 * ec1;

        f32x4 a0 = __builtin_amdgcn_mfma_f32_16x16x32_f16(WA00, B0, b40, 0, 0, 0);
        f32x4 a1 = __builtin_amdgcn_mfma_f32_16x16x32_f16(WA10, B0, b41, 0, 0, 0);
        f32x4 a2 = __builtin_amdgcn_mfma_f32_16x16x32_f16(WA20, B0, b42, 0, 0, 0);
        f32x4 a3 = __builtin_amdgcn_mfma_f32_16x16x32_f16(WA30, B0, b43, 0, 0, 0);
        f32x4 aq = __builtin_amdgcn_mfma_f32_16x16x32_f16(PA0,  B0, z4,  0, 0, 0);
        a0 = __builtin_amdgcn_mfma_f32_16x16x32_f16(WA01, B1, a0, 0, 0, 0);
        a1 = __builtin_amdgcn_mfma_f32_16x16x32_f16(WA11, B1, a1, 0, 0, 0);
        a2 = __builtin_amdgcn_mfma_f32_16x16x32_f16(WA21, B1, a2, 0, 0, 0);
        a3 = __builtin_amdgcn_mfma_f32_16x16x32_f16(WA31, B1, a3, 0, 0, 0);
        aq = __builtin_amdgcn_mfma_f32_16x16x32_f16(PA1,  B1, aq, 0, 0, 0);

        float s0 = fmaxf(a0[0], 0.f) * h40[0];
        float s1 = fmaxf(a1[0], 0.f) * h41[0];
        float s2 = fmaxf(a2[0], 0.f) * h42[0];
        float s3 = fmaxf(a3[0], 0.f) * h43[0];
        s0 = fmaf(fmaxf(a0[1], 0.f), h40[1], s0);
        s1 = fmaf(fmaxf(a1[1], 0.f), h41[1], s1);
        s2 = fmaf(fmaxf(a2[1], 0.f), h42[1], s2);
        s3 = fmaf(fmaxf(a3[1], 0.f), h43[1], s3);
        s0 = fmaf(fmaxf(a0[2], 0.f), h40[2], s0);
        s1 = fmaf(fmaxf(a1[2], 0.f), h41[2], s1);
        s2 = fmaf(fmaxf(a2[2], 0.f), h42[2], s2);
        s3 = fmaf(fmaxf(a3[2], 0.f), h43[2], s3);
        s0 = fmaf(fmaxf(a0[3], 0.f), h40[3], s0);
        s1 = fmaf(fmaxf(a1[3], 0.f), h41[3], s1);
        s2 = fmaf(fmaxf(a2[3], 0.f), h42[3], s2);
        s3 = fmaf(fmaxf(a3[3], 0.f), h43[3], s3);
        float ts = (s0 + s1) + (s2 + s3);
        ts += __shfl_xor(ts, 16);
        ts += __shfl_xor(ts, 32);

        if (lg == 0 && p < NUM_P) {
            sq_s[row][p] = make_float2(ts, aq[0]);
        }
    }
    __syncthreads();

    // ---------------- phase 3: per-row softmax + pooling ----------------
    // wave w covers slots t2 = (w&3)*64 + lane of row (w>>2)
    const int t2 = wv * 64 + lane;
    float sv0, sv1, sv2, qv0, qv1, qv2;
    {
        float2 x0 = sq_s[row][t2];
        float2 x1 = sq_s[row][t2 + 256];
        bool ok2 = (t2 + 512) < NUM_P;
        float2 x2 = ok2 ? sq_s[row][t2 + 512] : make_float2(-1e30f, 0.f);
        sv0 = x0.x; qv0 = x0.y;
        sv1 = x1.x; qv1 = x1.y;
        sv2 = x2.x; qv2 = x2.y;
        if (t2 + 256 >= NUM_P) { sv1 = -1e30f; qv1 = 0.f; }
        if (t2 >= NUM_P)       { sv0 = -1e30f; qv0 = 0.f; }
    }

    float m3 = fmaxf(fmaxf(sv0, sv1), sv2);
    #pragma unroll
    for (int mm = 1; mm < 64; mm <<= 1) m3 = fmaxf(m3, __shfl_xor(m3, mm));
    if (lane == 0) wredM[wave] = m3;
    __syncthreads();
    const float M = fmaxf(fmaxf(wredM[row * 4 + 0], wredM[row * 4 + 1]),
                          fmaxf(wredM[row * 4 + 2], wredM[row * 4 + 3]));

    float e0 = __expf(sv0 - M);
    float e1 = __expf(sv1 - M);
    float e2 = __expf(sv2 - M);
    float S  = e0 + e1 + e2;
    float Q  = fmaf(e0, qv0, fmaf(e1, qv1, e2 * qv2));
    #pragma unroll
    for (int mm = 1; mm < 64; mm <<= 1) {
        S += __shfl_xor(S, mm);
        Q += __shfl_xor(Q, mm);
    }
    if (lane == 0) { wredS[wave] = S; wredQ[wave] = Q; }
    __syncthreads();

    if (t == 0 || t == 256) {
        const int r4 = row * 4;
        const float Ssum = wredS[r4] + wredS[r4 + 1] + wredS[r4 + 2] + wredS[r4 + 3];
        const float Qsum = wredQ[r4] + wredQ[r4 + 1] + wredQ[r4 + 2] + wredQ[r4 + 3];
        const float att_pool = Qsum / Ssum;
        const float x = bias[0] + s_yfirst[row] + att_pool;
        out[blk * 2 + row] = 1.f / (1.f + __expf(-x));
    }
}

extern "C" void kernel_launch(void* const* d_in, const int* in_sizes, int n_in,
                              void* d_out, int out_size, void* d_ws, size_t ws_size,
                              hipStream_t stream) {
    const int*   feat_index = (const int*)  d_in[0];
    const float* feat_value = (const float*)d_in[1];
    const float* fo_w       = (const float*)d_in[2];
    const float* emb_table  = (const float*)d_in[3];
    const float* att_W      = (const float*)d_in[4];
    const float* att_b      = (const float*)d_in[5];
    const float* att_h      = (const float*)d_in[6];
    const float* p_vec      = (const float*)d_in[7];
    const float* bias       = (const float*)d_in[8];
    float*       out        = (float*)d_out;

    const int B = in_sizes[0] / NUM_F;   // 2048

    afm_2row<<<B / 2, 512, 0, stream>>>(feat_index, feat_value, fo_w, emb_table,
                                        att_W, att_b, att_h, p_vec, bias, out);
}